// Round 3
// baseline (29.694 us; speedup 1.0000x reference)
//
#include <hip/hip_runtime.h>

// Problem shape (fixed by reference setup_inputs):
//   x: [B=32, C=256, H=64, W=64] fp32, conv_w: [1,1,3] fp32
//   out: [B, 3, H, W] fp32
#define B  32
#define C  256
#define HW 4096          // 64*64
#define BC (B * C)       // 8192

// ---------------------------------------------------------------------------
// Kernel 1: per-(b,c) spatial mean. ONE WAVE per slice: 64 lanes x 16 float4.
// 4 independent accumulators so all 16 loads issue before the sum chain.
// 2048 blocks x 256 threads = 8192 waves = 8192 slices.
// ---------------------------------------------------------------------------
__global__ __launch_bounds__(256) void eca_mean_kernel(
    const float* __restrict__ x, float* __restrict__ means) {
    const int wid  = (blockIdx.x * 256 + threadIdx.x) >> 6;  // slice id
    const int lane = threadIdx.x & 63;
    const float4* p4 = reinterpret_cast<const float4*>(x + (size_t)wid * HW);

    float s0 = 0.f, s1 = 0.f, s2 = 0.f, s3 = 0.f;
#pragma unroll
    for (int i = 0; i < 4; ++i) {
        float4 a = p4[lane + (4 * i + 0) * 64];
        float4 b = p4[lane + (4 * i + 1) * 64];
        float4 c = p4[lane + (4 * i + 2) * 64];
        float4 d = p4[lane + (4 * i + 3) * 64];
        s0 += (a.x + a.y) + (a.z + a.w);
        s1 += (b.x + b.y) + (b.z + b.w);
        s2 += (c.x + c.y) + (c.z + c.w);
        s3 += (d.x + d.y) + (d.z + d.w);
    }
    float sum = (s0 + s1) + (s2 + s3);
#pragma unroll
    for (int off = 32; off > 0; off >>= 1)
        sum += __shfl_xor(sum, off);

    if (lane == 0) means[wid] = sum * (1.0f / HW);
}

// ---------------------------------------------------------------------------
// Kernel 2: fused conv1d(k=3,SAME) + top-3 + gather.
// Grid: 32 batches x 12 chunks = 384 blocks, 256 threads (one per channel).
//
// Top-3: sigmoid monotonic -> skip. Key = (monotonic_u32(y) << 8) | (255-c)
// so max-reduce picks larger value, smaller channel on ties (lax.top_k
// semantics). Each wave finds ITS top-3 of its 64 channels via butterfly
// shfl_xor (all lanes see the max -> no broadcast, no barrier), with
// in-register exclusion across 3 rounds. One __syncthreads to share the
// 4x3 candidates in LDS; every thread then scans 12 candidates (uniform).
// ---------------------------------------------------------------------------
__global__ __launch_bounds__(256) void eca_fused_kernel(
    const float* __restrict__ x, const float* __restrict__ means,
    const float* __restrict__ w, float* __restrict__ out) {
    const int b  = blockIdx.x / 12;
    const int j  = blockIdx.x % 12;
    const int jj = j >> 2;   // which of the 3 output slices
    const int q  = j & 3;    // which quarter of the slice
    const int c  = threadIdx.x;
    const int wave = c >> 6;

    const float* m = means + b * C;
    const float ym1 = (c > 0)     ? m[c - 1] : 0.f;  // SAME zero-pad
    const float y0  = m[c];
    const float yp1 = (c < C - 1) ? m[c + 1] : 0.f;
    const float y = w[0] * ym1 + w[1] * y0 + w[2] * yp1;

    // Monotonic float->uint (total order matching float compare)
    unsigned int u = __float_as_uint(y);
    u = (u & 0x80000000u) ? ~u : (u | 0x80000000u);
    const unsigned long long key =
        ((unsigned long long)u << 8) | (unsigned long long)(255 - c);

    __shared__ unsigned long long cand[12];

    bool excluded = false;
#pragma unroll
    for (int r = 0; r < 3; ++r) {
        unsigned long long k = excluded ? 0ULL : key;
#pragma unroll
        for (int off = 32; off > 0; off >>= 1) {
            unsigned long long o = __shfl_xor(k, off);
            k = (o > k) ? o : k;
        }
        // k is uniform across the wave = this wave's round-r winner
        if ((c & 63) == 0) cand[wave * 3 + r] = k;
        if (key == k) excluded = true;
    }
    __syncthreads();

    // Every thread: top-3 of the 12 candidates (uniform, divergence-free).
    unsigned long long k0 = 0, k1 = 0, k2 = 0;
#pragma unroll
    for (int i = 0; i < 12; ++i) {
        const unsigned long long v = cand[i];
        if (v > k0)      { k2 = k1; k1 = k0; k0 = v; }
        else if (v > k1) { k2 = k1; k1 = v; }
        else if (v > k2) { k2 = v; }
    }
    const unsigned long long kw = (jj == 0) ? k0 : (jj == 1) ? k1 : k2;
    const int mych = 255 - (int)(kw & 0xFFULL);

    // Copy quarter q of slice (b, mych) -> out slice (b, jj).
    const float4* src = reinterpret_cast<const float4*>(
        x + ((size_t)(b * C + mych)) * HW);
    float4* dst = reinterpret_cast<float4*>(
        out + ((size_t)(b * 3 + jj)) * HW);
    const int o = q * 256 + c;   // 1024 float4 per slice, 256 per quarter
    dst[o] = src[o];
}

extern "C" void kernel_launch(void* const* d_in, const int* in_sizes, int n_in,
                              void* d_out, int out_size, void* d_ws, size_t ws_size,
                              hipStream_t stream) {
    const float* x      = (const float*)d_in[0];
    const float* conv_w = (const float*)d_in[1];
    float* out = (float*)d_out;

    float* means = (float*)d_ws;   // 8192 f32 = 32 KB

    eca_mean_kernel<<<BC / 4, 256, 0, stream>>>(x, means);
    eca_fused_kernel<<<B * 12, 256, 0, stream>>>(x, means, conv_w, out);
}

// Round 5
// 29.278 us; speedup vs baseline: 1.0142x; 1.0142x over previous
//
#include <hip/hip_runtime.h>

// Problem shape (fixed by reference setup_inputs):
//   x: [B=32, C=256, H=64, W=64] fp32, conv_w: [1,1,3] fp32
//   out: [B, 3, H, W] fp32
#define B  32
#define C  256
#define HW 4096          // 64*64
#define BC (B * C)       // 8192

// ---------------------------------------------------------------------------
// Kernel 1: per-(b,c) spatial mean. ONE WAVE per 2 contiguous slices (32 KB)
// to amortize per-wave fixed cost; slices processed sequentially so 16 loads
// stay in flight with ~70 VGPRs (no occupancy cliff).
// 1024 blocks x 256 threads = 4096 waves x 2 slices = 8192 slices.
// ---------------------------------------------------------------------------
__global__ __launch_bounds__(256) void eca_mean_kernel(
    const float* __restrict__ x, float* __restrict__ means) {
    const int wid  = (blockIdx.x * 256 + threadIdx.x) >> 6;  // wave 0..4095
    const int lane = threadIdx.x & 63;
    const float4* x4 = reinterpret_cast<const float4*>(x);

#pragma unroll
    for (int s = 0; s < 2; ++s) {
        const int slice = wid * 2 + s;                 // 0..8191
        const float4* p4 = x4 + (size_t)slice * (HW / 4);
        float s0 = 0.f, s1 = 0.f, s2 = 0.f, s3 = 0.f;
#pragma unroll
        for (int i = 0; i < 4; ++i) {
            float4 a = p4[lane + (4 * i + 0) * 64];
            float4 b = p4[lane + (4 * i + 1) * 64];
            float4 c = p4[lane + (4 * i + 2) * 64];
            float4 d = p4[lane + (4 * i + 3) * 64];
            s0 += (a.x + a.y) + (a.z + a.w);
            s1 += (b.x + b.y) + (b.z + b.w);
            s2 += (c.x + c.y) + (c.z + c.w);
            s3 += (d.x + d.y) + (d.z + d.w);
        }
        float sum = (s0 + s1) + (s2 + s3);
#pragma unroll
        for (int off = 32; off > 0; off >>= 1)
            sum += __shfl_xor(sum, off);
        if (lane == 0) means[slice] = sum * (1.0f / HW);
    }
}

// ---------------------------------------------------------------------------
// Kernel 2 (unchanged from R2, proven): fused conv1d(k=3,SAME) + top-3 +
// gather. Grid: 32 batches x 12 chunks = 384 blocks, 256 threads.
// Sigmoid monotonic -> skipped. Key = (mono_u32(y)<<8) | (255-c) reproduces
// lax.top_k's smaller-index tie-break under max-reduce.
// ---------------------------------------------------------------------------
__global__ __launch_bounds__(256) void eca_fused_kernel(
    const float* __restrict__ x, const float* __restrict__ means,
    const float* __restrict__ w, float* __restrict__ out) {
    const int b  = blockIdx.x / 12;
    const int j  = blockIdx.x % 12;
    const int jj = j >> 2;   // which of the 3 output slices
    const int q  = j & 3;    // which quarter of the slice
    const int c  = threadIdx.x;
    const int wave = c >> 6;

    const float* m = means + b * C;
    const float ym1 = (c > 0)     ? m[c - 1] : 0.f;  // SAME zero-pad
    const float y0  = m[c];
    const float yp1 = (c < C - 1) ? m[c + 1] : 0.f;
    const float y = w[0] * ym1 + w[1] * y0 + w[2] * yp1;

    // Monotonic float->uint (total order matching float compare)
    unsigned int u = __float_as_uint(y);
    u = (u & 0x80000000u) ? ~u : (u | 0x80000000u);
    const unsigned long long key =
        ((unsigned long long)u << 8) | (unsigned long long)(255 - c);

    __shared__ unsigned long long cand[12];

    bool excluded = false;
#pragma unroll
    for (int r = 0; r < 3; ++r) {
        unsigned long long k = excluded ? 0ULL : key;
#pragma unroll
        for (int off = 32; off > 0; off >>= 1) {
            unsigned long long o = __shfl_xor(k, off);
            k = (o > k) ? o : k;
        }
        if ((c & 63) == 0) cand[wave * 3 + r] = k;
        if (key == k) excluded = true;
    }
    __syncthreads();

    unsigned long long k0 = 0, k1 = 0, k2 = 0;
#pragma unroll
    for (int i = 0; i < 12; ++i) {
        const unsigned long long v = cand[i];
        if (v > k0)      { k2 = k1; k1 = k0; k0 = v; }
        else if (v > k1) { k2 = k1; k1 = v; }
        else if (v > k2) { k2 = v; }
    }
    const unsigned long long kw = (jj == 0) ? k0 : (jj == 1) ? k1 : k2;
    const int mych = 255 - (int)(kw & 0xFFULL);

    // Copy quarter q of slice (b, mych) -> out slice (b, jj).
    const float4* src = reinterpret_cast<const float4*>(
        x + ((size_t)(b * C + mych)) * HW);
    float4* dst = reinterpret_cast<float4*>(
        out + ((size_t)(b * 3 + jj)) * HW);
    const int o = q * 256 + c;   // 1024 float4 per slice, 256 per quarter
    dst[o] = src[o];
}

extern "C" void kernel_launch(void* const* d_in, const int* in_sizes, int n_in,
                              void* d_out, int out_size, void* d_ws, size_t ws_size,
                              hipStream_t stream) {
    const float* x      = (const float*)d_in[0];
    const float* conv_w = (const float*)d_in[1];
    float* out = (float*)d_out;

    float* means = (float*)d_ws;   // 8192 f32 = 32 KB

    eca_mean_kernel<<<BC / 8, 256, 0, stream>>>(x, means);
    eca_fused_kernel<<<B * 12, 256, 0, stream>>>(x, means, conv_w, out);
}